// Round 3
// baseline (392.914 us; speedup 1.0000x reference)
//
#include <hip/hip_runtime.h>
#include <hip/hip_cooperative_groups.h>

namespace cg = cooperative_groups;

#define B_    1
#define N_    6
#define C_    80
#define D_    112
#define HF_   16
#define WF_   44
#define NX_   128
#define NY_   128
#define NZ_   1
#define BN_   (B_ * N_)
#define HW_   (HF_ * WF_)
#define NPIX_ (NZ_ * NX_ * NY_)     // 16384
#define P_    (BN_ * HW_)           // 4224
#define ENTCAP_ (P_ * D_)           // 473088 worst-case entries
#define NBLK_ 512                   // cooperative grid (must be co-resident; 256 CUs x >=2)

// ---------------- 3x3 inverse (adjugate) ----------------
__device__ __forceinline__ void inv3(const float* m, float* o) {
    float a = m[0], b = m[1], c = m[2];
    float d = m[3], e = m[4], f = m[5];
    float g = m[6], h = m[7], i = m[8];
    float A  =  (e * i - f * h);
    float Bc = -(d * i - f * g);
    float Cc =  (d * h - e * g);
    float det = a * A + b * Bc + c * Cc;
    float id = 1.0f / det;
    o[0] = A * id;                  o[1] = -(b * i - c * h) * id;   o[2] =  (b * f - c * e) * id;
    o[3] = Bc * id;                 o[4] =  (a * i - c * g) * id;   o[5] = -(a * f - c * d) * id;
    o[6] = Cc * id;                 o[7] = -(a * h - b * g) * id;   o[8] =  (a * e - b * d) * id;
}

__device__ __forceinline__ int voxel_of(float xs, float ys, float dv,
                                        const float* ip, const float* cmb,
                                        float ptx, float pty, float ptz,
                                        float trx, float trY, float trz) {
    float p0x = xs - ptx, p0y = ys - pty, p0z = dv - ptz;
    float p1x = ip[0]*p0x + ip[1]*p0y + ip[2]*p0z;
    float p1y = ip[3]*p0x + ip[4]*p0y + ip[5]*p0z;
    float p1z = ip[6]*p0x + ip[7]*p0y + ip[8]*p0z;
    float qx = p1x * p1z, qy = p1y * p1z, qz = p1z;
    float rx = cmb[0]*qx + cmb[1]*qy + cmb[2]*qz + trx;
    float ry = cmb[3]*qx + cmb[4]*qy + cmb[5]*qz + trY;
    float rz = cmb[6]*qx + cmb[7]*qy + cmb[8]*qz + trz;
    const float lox = -50.8f - 0.4f;   // bx - dx/2 folded in f32, matches np
    const float loy = -50.8f - 0.4f;
    const float loz = -10.0f;
    int ix = (int)((rx - lox) / 0.8f);   // trunc toward zero == astype(int32)
    int iy = (int)((ry - loy) / 0.8f);
    int iz = (int)((rz - loz) / 20.0f);
    bool val = (ix >= 0) && (ix < NX_) && (iy >= 0) && (iy < NY_) && (iz >= 0) && (iz < NZ_);
    return val ? ((iz * NX_ + ix) * NY_ + iy) : -1;
}

// ===================== single cooperative fused kernel =====================
__global__ __launch_bounds__(256, 4) void fused_kernel(
    const float* __restrict__ rots, const float* __restrict__ trans,
    const float* __restrict__ intrins, const float* __restrict__ post_rots,
    const float* __restrict__ post_trans,
    const float* __restrict__ img_feat, const float* __restrict__ depth_digit,
    float* __restrict__ outp, float* __restrict__ featT,
    int4* __restrict__ entries, int2* __restrict__ csr,
    int* __restrict__ hist, int* __restrict__ scanned,
    int* __restrict__ segsum, int* __restrict__ gE)
{
    cg::grid_group grid = cg::this_grid();
    const int tid  = threadIdx.x;
    const int lane = tid & 63;
    const int wave = tid >> 6;
    const int bid  = blockIdx.x;

    __shared__ int   s_scan[256];
    __shared__ int   s_segoff[64];
    __shared__ int   s_k[128];
    __shared__ float s_w[128];

    // ---- P0: zero hist + global entry counter ----
    for (int i = bid * 256 + tid; i < NPIX_; i += NBLK_ * 256) hist[i] = 0;
    if (bid == 0 && tid == 0) *gE = 0;
    grid.sync();

    // ---- P1: wave-per-pixel softmax + geometry + entry emission ----
    for (int p = bid * 4 + wave; p < P_; p += NBLK_ * 4) {
        int hw = p % HW_;
        int bn = p / HW_;
        int w = hw % WF_, h = hw / WF_;

        // feat transpose: featT[p][c] = img_feat[bn][c][hw]
        featT[(size_t)p * C_ + lane] = img_feat[((size_t)bn * C_ + lane) * HW_ + hw];
        if (lane < C_ - 64)
            featT[(size_t)p * C_ + 64 + lane] = img_feat[((size_t)bn * C_ + 64 + lane) * HW_ + hw];

        // softmax over D=112 bins, 2 bins per lane (lanes 0..55)
        bool act = lane < 56;
        int b0 = 2 * lane, b1 = 2 * lane + 1;
        float l0 = act ? depth_digit[((size_t)bn * D_ + b0) * HW_ + hw] : -INFINITY;
        float l1 = act ? depth_digit[((size_t)bn * D_ + b1) * HW_ + hw] : -INFINITY;
        float m = fmaxf(l0, l1);
        #pragma unroll
        for (int o = 32; o > 0; o >>= 1) m = fmaxf(m, __shfl_xor(m, o));
        float e0 = act ? __expf(l0 - m) : 0.0f;
        float e1 = act ? __expf(l1 - m) : 0.0f;
        float s = e0 + e1;
        #pragma unroll
        for (int o = 32; o > 0; o >>= 1) s += __shfl_xor(s, o);
        float inv = 1.0f / s;
        float pr0 = e0 * inv, pr1 = e1 * inv;

        // per-camera matrices (bn is wave-uniform -> scalar loads/regs)
        float ip[9], ii[9], cmb[9];
        inv3(post_rots + bn * 9, ip);
        inv3(intrins + bn * 9, ii);
        const float* ro = rots + bn * 9;
        #pragma unroll
        for (int r = 0; r < 3; ++r)
            #pragma unroll
            for (int c = 0; c < 3; ++c)
                cmb[r * 3 + c] = ro[r * 3 + 0] * ii[0 * 3 + c] +
                                 ro[r * 3 + 1] * ii[1 * 3 + c] +
                                 ro[r * 3 + 2] * ii[2 * 3 + c];
        float ptx = post_trans[bn * 3 + 0], pty = post_trans[bn * 3 + 1], ptz = post_trans[bn * 3 + 2];
        float trx = trans[bn * 3 + 0],      trY = trans[bn * 3 + 1],      trz = trans[bn * 3 + 2];

        float xs = (float)((double)w * (703.0 / 43.0));  // np.linspace(0,703,44)
        float ys = (float)h * 17.0f;                     // np.linspace(0,255,16)

        int v0 = act ? voxel_of(xs, ys, 2.0f + 0.5f * (float)b0, ip, cmb, ptx, pty, ptz, trx, trY, trz) : -1;
        int v1 = act ? voxel_of(xs, ys, 2.0f + 0.5f * (float)b1, ip, cmb, ptx, pty, ptz, trx, trY, trz) : -1;

        bool a0 = v0 >= 0, a1 = v1 >= 0;
        unsigned long long m0 = __ballot(a0);
        unsigned long long m1 = __ballot(a1);
        int total = __popcll(m0) + __popcll(m1);
        int base = 0;
        if (lane == 0) base = atomicAdd(gE, total);
        base = __shfl(base, 0);
        unsigned long long below = ((unsigned long long)1 << lane) - 1;
        if (a0) {
            int idx = base + __popcll(m0 & below);
            int r = atomicAdd(&hist[v0], 1);
            entries[idx] = make_int4(v0, p, __float_as_int(pr0), r);
        }
        if (a1) {
            int idx = base + __popcll(m0) + __popcll(m1 & below);
            int r = atomicAdd(&hist[v1], 1);
            entries[idx] = make_int4(v1, p, __float_as_int(pr1), r);
        }
    }
    grid.sync();

    // ---- P2: blocks 0..63 scan hist segments; blocks 64+ zero output ----
    if (bid < 64) {
        int bin = bid * 256 + tid;
        int v = hist[bin];
        s_scan[tid] = v;
        __syncthreads();
        for (int o = 1; o < 256; o <<= 1) {
            int t_ = (tid >= o) ? s_scan[tid - o] : 0;
            __syncthreads();
            s_scan[tid] += t_;
            __syncthreads();
        }
        scanned[bin] = s_scan[tid] - v;            // exclusive within segment
        if (tid == 255) segsum[bid] = s_scan[255]; // segment total
    } else {
        float4* o4 = (float4*)outp;
        const int tot4 = C_ * NPIX_ / 4;
        for (int i = (bid - 64) * 256 + tid; i < tot4; i += (NBLK_ - 64) * 256)
            o4[i] = make_float4(0.f, 0.f, 0.f, 0.f);
    }
    grid.sync();

    // ---- P3: scatter entries into voxel-sorted CSR (no atomics) ----
    if (tid < 64) {
        int x = segsum[tid];
        int inc = x;
        #pragma unroll
        for (int o = 1; o < 64; o <<= 1) {
            int y = __shfl_up(inc, o);
            if (lane >= o) inc += y;
        }
        s_segoff[tid] = inc - x;   // exclusive scan of segment sums
    }
    __syncthreads();
    int E = *gE;
    for (int i = bid * 256 + tid; i < E; i += NBLK_ * 256) {
        int4 e = entries[i];
        int pos = s_segoff[e.x >> 8] + scanned[e.x] + e.w;
        csr[pos] = make_int2((e.x << 13) | e.y, e.z);   // key: vox<<13 | pix
    }
    grid.sync();

    // ---- P4: entry-chunked segmented gather (load-balanced) ----
    for (int base = bid * 128; base < E; base += NBLK_ * 128) {
        int n = min(128, E - base);
        if (tid < n) {
            int2 e = csr[base + tid];
            s_k[tid] = e.x;
            s_w[tid] = __int_as_float(e.y);
        }
        __syncthreads();
        int eg = tid >> 7;          // entry group 0/1 (64 entries each)
        int c  = tid & 127;         // channel (active if < 80)
        int lo = eg * 64, hi = min(lo + 64, n);
        if (c < C_) {
            float acc = 0.0f;
            int cur = -1;
            for (int i = lo; i < hi; ++i) {
                int key = s_k[i];
                int v = key >> 13;
                int px = key & 8191;
                if (v != cur) {
                    if (cur >= 0) atomicAdd(&outp[(size_t)c * NPIX_ + cur], acc);
                    cur = v; acc = 0.0f;
                }
                acc = fmaf(s_w[i], featT[(size_t)px * C_ + c], acc);
            }
            if (cur >= 0) atomicAdd(&outp[(size_t)c * NPIX_ + cur], acc);
        }
        __syncthreads();
    }
}

// ===================== fallback path (round-1 proven) =====================
__global__ void prep_mats_kernel(const float* __restrict__ rots,
                                 const float* __restrict__ trans,
                                 const float* __restrict__ intrins,
                                 const float* __restrict__ post_rots,
                                 const float* __restrict__ post_trans,
                                 float* __restrict__ mats) {
    int bn = threadIdx.x;
    if (bn >= BN_) return;
    float ip[9], ii[9];
    inv3(post_rots + bn * 9, ip);
    inv3(intrins + bn * 9, ii);
    const float* ro = rots + bn * 9;
    float* out = mats + bn * 24;
    #pragma unroll
    for (int r = 0; r < 3; ++r)
        #pragma unroll
        for (int c = 0; c < 3; ++c)
            out[9 + r * 3 + c] = ro[r * 3 + 0] * ii[0 * 3 + c] +
                                 ro[r * 3 + 1] * ii[1 * 3 + c] +
                                 ro[r * 3 + 2] * ii[2 * 3 + c];
    #pragma unroll
    for (int k = 0; k < 9; ++k) out[k] = ip[k];
    #pragma unroll
    for (int k = 0; k < 3; ++k) { out[18 + k] = post_trans[bn * 3 + k]; out[21 + k] = trans[bn * 3 + k]; }
}

__global__ __launch_bounds__(128) void scatter_kernel(const float* __restrict__ img_feat,
                                                      const float* __restrict__ depth_digit,
                                                      const float* __restrict__ mats,
                                                      float* __restrict__ outp) {
    int blk = blockIdx.x;
    int w  = blk % WF_;
    int h  = (blk / WF_) % HF_;
    int bn = blk / HW_;
    int b  = bn / N_;
    int tid = threadIdx.x;
    __shared__ float sm[24];
    __shared__ float s_feat[C_];
    __shared__ float s_prob[D_];
    __shared__ int   s_vox[D_];
    __shared__ float s_red[128];
    __shared__ float s_mw[D_];
    __shared__ int   s_mvox[D_];
    __shared__ int   s_cnt;
    if (tid < 24) sm[tid] = mats[bn * 24 + tid];
    if (tid < C_) s_feat[tid] = img_feat[((size_t)bn * C_ + tid) * HW_ + h * WF_ + w];
    float logit = -INFINITY;
    if (tid < D_) logit = depth_digit[((size_t)bn * D_ + tid) * HW_ + h * WF_ + w];
    s_red[tid] = logit;
    __syncthreads();
    #pragma unroll
    for (int s = 64; s > 0; s >>= 1) {
        if (tid < s) s_red[tid] = fmaxf(s_red[tid], s_red[tid + s]);
        __syncthreads();
    }
    float mx = s_red[0];
    __syncthreads();
    float e = (tid < D_) ? __expf(logit - mx) : 0.0f;
    s_red[tid] = e;
    __syncthreads();
    #pragma unroll
    for (int s = 64; s > 0; s >>= 1) {
        if (tid < s) s_red[tid] += s_red[tid + s];
        __syncthreads();
    }
    float inv_sum = 1.0f / s_red[0];
    if (tid < D_) s_prob[tid] = e * inv_sum;
    if (tid < D_) {
        float dval = 2.0f + 0.5f * (float)tid;
        float xs = (float)((double)w * (703.0 / 43.0));
        float ys = (float)h * 17.0f;
        s_vox[tid] = voxel_of(xs, ys, dval, sm, sm + 9, sm[18], sm[19], sm[20], sm[21], sm[22], sm[23]);
    }
    __syncthreads();
    if (tid == 0) {
        int cnt = 0, last = -1;
        float wsum = 0.0f;
        for (int d0 = 0; d0 < D_; ++d0) {
            int v = s_vox[d0];
            if (v < 0) continue;
            if (v == last) { wsum += s_prob[d0]; }
            else {
                if (last >= 0) { s_mvox[cnt] = last; s_mw[cnt] = wsum; ++cnt; }
                last = v; wsum = s_prob[d0];
            }
        }
        if (last >= 0) { s_mvox[cnt] = last; s_mw[cnt] = wsum; ++cnt; }
        s_cnt = cnt;
    }
    __syncthreads();
    int cnt = s_cnt;
    int total = cnt * C_;
    for (int k = tid; k < total; k += 128) {
        int i = k / C_;
        int c = k - i * C_;
        int pixv = s_mvox[i];
        atomicAdd(outp + ((size_t)(b * C_ + c)) * NPIX_ + pixv, s_mw[i] * s_feat[c]);
    }
}

extern "C" void kernel_launch(void* const* d_in, const int* in_sizes, int n_in,
                              void* d_out, int out_size, void* d_ws, size_t ws_size,
                              hipStream_t stream) {
    const float* rots        = (const float*)d_in[1];
    const float* trans       = (const float*)d_in[2];
    const float* intrins     = (const float*)d_in[3];
    const float* post_rots   = (const float*)d_in[4];
    const float* post_trans  = (const float*)d_in[5];
    const float* img_feat    = (const float*)d_in[6];
    const float* depth_digit = (const float*)d_in[7];
    float* outp = (float*)d_out;

    // workspace layout
    const size_t entries_b = (size_t)ENTCAP_ * 16;
    const size_t csr_b     = (size_t)ENTCAP_ * 8;
    const size_t featT_b   = (size_t)P_ * C_ * 4;
    const size_t hist_b    = (size_t)NPIX_ * 4;
    const size_t scanned_b = (size_t)NPIX_ * 4;
    const size_t seg_b     = 256;
    const size_t gE_b      = 256;
    const size_t need = entries_b + csr_b + featT_b + hist_b + scanned_b + seg_b + gE_b;

    bool ok = false;
    if (ws_size >= need) {
        char* pp = (char*)d_ws;
        int4*  entries = (int4*)pp;  pp += entries_b;
        int2*  csr     = (int2*)pp;  pp += csr_b;
        float* featT   = (float*)pp; pp += featT_b;
        int*   hist    = (int*)pp;   pp += hist_b;
        int*   scanned = (int*)pp;   pp += scanned_b;
        int*   segsum  = (int*)pp;   pp += seg_b;
        int*   gE      = (int*)pp;

        void* args[] = {
            (void*)&rots, (void*)&trans, (void*)&intrins, (void*)&post_rots,
            (void*)&post_trans, (void*)&img_feat, (void*)&depth_digit,
            (void*)&outp, (void*)&featT, (void*)&entries, (void*)&csr,
            (void*)&hist, (void*)&scanned, (void*)&segsum, (void*)&gE
        };
        hipError_t err = hipLaunchCooperativeKernel(fused_kernel, dim3(NBLK_), dim3(256),
                                                    args, 0u, stream);
        ok = (err == hipSuccess);
    }

    if (!ok) {
        // fallback: proven round-1 atomic scatter (needs only 576B of ws)
        float* mats = (float*)d_ws;
        prep_mats_kernel<<<1, 64, 0, stream>>>(rots, trans, intrins, post_rots, post_trans, mats);
        hipMemsetAsync(outp, 0, (size_t)out_size * sizeof(float), stream);
        scatter_kernel<<<P_, 128, 0, stream>>>(img_feat, depth_digit, mats, outp);
    }
}

// Round 4
// 107.492 us; speedup vs baseline: 3.6553x; 3.6553x over previous
//
#include <hip/hip_runtime.h>

#define B_    1
#define N_    6
#define C_    80
#define D_    112
#define HF_   16
#define WF_   44
#define NX_   128
#define NY_   128
#define NZ_   1
#define HW_   (HF_ * WF_)          // 704
#define NPIX_ (NZ_ * NX_ * NY_)    // 16384

// ---------------- 3x3 inverse (adjugate) ----------------
__device__ __forceinline__ void inv3(const float* m, float* o) {
    float a = m[0], b = m[1], c = m[2];
    float d = m[3], e = m[4], f = m[5];
    float g = m[6], h = m[7], i = m[8];
    float A  =  (e * i - f * h);
    float Bc = -(d * i - f * g);
    float Cc =  (d * h - e * g);
    float det = a * A + b * Bc + c * Cc;
    float id = 1.0f / det;
    o[0] = A * id;                  o[1] = -(b * i - c * h) * id;   o[2] =  (b * f - c * e) * id;
    o[3] = Bc * id;                 o[4] =  (a * i - c * g) * id;   o[5] = -(a * f - c * d) * id;
    o[6] = Cc * id;                 o[7] = -(a * h - b * g) * id;   o[8] =  (a * e - b * d) * id;
}

__device__ __forceinline__ int voxel_of(float xs, float ys, float dv, const float* sm) {
    const float* ip  = sm;       // invPost
    const float* cmb = sm + 9;   // rots @ inv(intrins)
    float ptx = sm[18], pty = sm[19], ptz = sm[20];
    float trx = sm[21], trY = sm[22], trz = sm[23];
    float p0x = xs - ptx, p0y = ys - pty, p0z = dv - ptz;
    float p1x = ip[0]*p0x + ip[1]*p0y + ip[2]*p0z;
    float p1y = ip[3]*p0x + ip[4]*p0y + ip[5]*p0z;
    float p1z = ip[6]*p0x + ip[7]*p0y + ip[8]*p0z;
    float qx = p1x * p1z, qy = p1y * p1z, qz = p1z;
    float rx = cmb[0]*qx + cmb[1]*qy + cmb[2]*qz + trx;
    float ry = cmb[3]*qx + cmb[4]*qy + cmb[5]*qz + trY;
    float rz = cmb[6]*qx + cmb[7]*qy + cmb[8]*qz + trz;
    const float lox = -50.8f - 0.4f;   // bx - dx/2, f32 fold matches np
    const float loy = -50.8f - 0.4f;
    const float loz = -10.0f;
    int ix = (int)((rx - lox) / 0.8f);   // trunc toward zero == astype(int32)
    int iy = (int)((ry - loy) / 0.8f);
    int iz = (int)((rz - loz) / 20.0f);
    bool val = (ix >= 0) && (ix < NX_) && (iy >= 0) && (iy < NY_) && (iz >= 0) && (iz < NZ_);
    return val ? ((iz * NX_ + ix) * NY_ + iy) : -1;
}

// One block per (h,w); all 6 cameras handled together.
// If the 6 per-camera voxel-run lists are identical (true when all cameras
// share geometry), emit ONE atomic per (run, channel) with the 6-camera
// weighted feature sum precomputed in registers — 6x fewer float atomics.
// Otherwise fall back to per-camera atomics (always correct).
__global__ __launch_bounds__(256) void scatter_merged(
    const float* __restrict__ rots, const float* __restrict__ trans,
    const float* __restrict__ intrins, const float* __restrict__ post_rots,
    const float* __restrict__ post_trans,
    const float* __restrict__ img_feat, const float* __restrict__ depth_digit,
    float* __restrict__ outp)
{
    const int hw = blockIdx.x;
    const int w  = hw % WF_;
    const int h  = hw / WF_;
    const int tid  = threadIdx.x;
    const int lane = tid & 63;
    const int wave = tid >> 6;

    __shared__ float s_prob[N_][D_];    // logits, overwritten with probs
    __shared__ float s_feat[N_][C_];
    __shared__ short s_vox[N_][D_];
    __shared__ short s_runv[N_][D_];
    __shared__ float s_runw[N_][D_];
    __shared__ float s_mat[N_][24];     // invPost[9], combine[9], post_trans[3], trans[3]
    __shared__ int   s_cnt[N_];
    __shared__ int   s_same;

    // ---- stage inputs ----
    for (int i = tid; i < N_ * D_; i += 256) {
        int cam = i / D_, d = i - cam * D_;
        s_prob[cam][d] = depth_digit[((size_t)cam * D_ + d) * HW_ + hw];
    }
    for (int i = tid; i < N_ * C_; i += 256) {
        int cam = i / C_, c = i - cam * C_;
        s_feat[cam][c] = img_feat[((size_t)cam * C_ + c) * HW_ + hw];
    }
    // per-camera matrices (6 threads)
    if (tid < N_) {
        float ipv[9], ii[9];
        inv3(post_rots + tid * 9, ipv);
        inv3(intrins + tid * 9, ii);
        const float* ro = rots + tid * 9;
        #pragma unroll
        for (int k = 0; k < 9; ++k) s_mat[tid][k] = ipv[k];
        #pragma unroll
        for (int r = 0; r < 3; ++r)
            #pragma unroll
            for (int c = 0; c < 3; ++c)
                s_mat[tid][9 + r * 3 + c] = ro[r*3+0]*ii[0*3+c] + ro[r*3+1]*ii[1*3+c] + ro[r*3+2]*ii[2*3+c];
        #pragma unroll
        for (int k = 0; k < 3; ++k) { s_mat[tid][18+k] = post_trans[tid*3+k]; s_mat[tid][21+k] = trans[tid*3+k]; }
    }
    __syncthreads();

    // ---- softmax per camera (wave-parallel; lanes 0..55 hold 2 bins each) ----
    for (int cc = wave; cc < N_; cc += 4) {
        bool act = lane < 56;
        float l0 = act ? s_prob[cc][lane]      : -INFINITY;
        float l1 = act ? s_prob[cc][lane + 56] : -INFINITY;
        float m = fmaxf(l0, l1);
        #pragma unroll
        for (int o = 32; o > 0; o >>= 1) m = fmaxf(m, __shfl_xor(m, o));
        float e0 = act ? __expf(l0 - m) : 0.0f;
        float e1 = act ? __expf(l1 - m) : 0.0f;
        float s = e0 + e1;
        #pragma unroll
        for (int o = 32; o > 0; o >>= 1) s += __shfl_xor(s, o);
        float inv = 1.0f / s;
        if (act) { s_prob[cc][lane] = e0 * inv; s_prob[cc][lane + 56] = e1 * inv; }
    }

    // ---- geometry: voxel per (cam, depth bin) ----
    {
        float xs = (float)((double)w * (703.0 / 43.0));  // np.linspace(0,703,44)
        float ys = (float)h * 17.0f;                     // np.linspace(0,255,16)
        for (int i = tid; i < N_ * D_; i += 256) {
            int cam = i / D_, d = i - cam * D_;
            float dval = 2.0f + 0.5f * (float)d;
            s_vox[cam][d] = (short)voxel_of(xs, ys, dval, s_mat[cam]);
        }
    }
    __syncthreads();

    // ---- run-length merge per camera (6 threads, serial over 112 bins) ----
    if (tid < N_) {
        int cnt = 0, last = -1;
        float wsum = 0.0f;
        #pragma unroll 4
        for (int d = 0; d < D_; ++d) {
            int v = s_vox[tid][d];
            if (v < 0) continue;
            if (v == last) { wsum += s_prob[tid][d]; }
            else {
                if (last >= 0) { s_runv[tid][cnt] = (short)last; s_runw[tid][cnt] = wsum; ++cnt; }
                last = v; wsum = s_prob[tid][d];
            }
        }
        if (last >= 0) { s_runv[tid][cnt] = (short)last; s_runw[tid][cnt] = wsum; ++cnt; }
        s_cnt[tid] = cnt;
    }
    __syncthreads();

    // ---- check run-structure equality across cameras ----
    if (tid == 0) {
        int same = 1, c0 = s_cnt[0];
        #pragma unroll
        for (int cam = 1; cam < N_; ++cam) same &= (s_cnt[cam] == c0);
        if (same) {
            for (int r = 0; r < c0 && same; ++r) {
                short v0 = s_runv[0][r];
                #pragma unroll
                for (int cam = 1; cam < N_; ++cam) same &= (s_runv[cam][r] == v0);
            }
        }
        s_same = same;
    }
    __syncthreads();

    // ---- emission ----
    if (s_same) {
        int cnt = s_cnt[0];
        int total = cnt * C_;
        for (int k = tid; k < total; k += 256) {
            int r = k / C_;
            int c = k - r * C_;
            int v = s_runv[0][r];
            float val = 0.0f;
            #pragma unroll
            for (int cam = 0; cam < N_; ++cam)
                val = fmaf(s_runw[cam][r], s_feat[cam][c], val);
            atomicAdd(&outp[(size_t)c * NPIX_ + v], val);
        }
    } else {
        for (int cam = 0; cam < N_; ++cam) {
            int cnt = s_cnt[cam];
            int total = cnt * C_;
            for (int k = tid; k < total; k += 256) {
                int r = k / C_;
                int c = k - r * C_;
                int v = s_runv[cam][r];
                atomicAdd(&outp[(size_t)c * NPIX_ + v], s_runw[cam][r] * s_feat[cam][c]);
            }
        }
    }
}

extern "C" void kernel_launch(void* const* d_in, const int* in_sizes, int n_in,
                              void* d_out, int out_size, void* d_ws, size_t ws_size,
                              hipStream_t stream) {
    const float* rots        = (const float*)d_in[1];
    const float* trans       = (const float*)d_in[2];
    const float* intrins     = (const float*)d_in[3];
    const float* post_rots   = (const float*)d_in[4];
    const float* post_trans  = (const float*)d_in[5];
    const float* img_feat    = (const float*)d_in[6];
    const float* depth_digit = (const float*)d_in[7];
    float* outp = (float*)d_out;

    hipMemsetAsync(outp, 0, (size_t)out_size * sizeof(float), stream);
    scatter_merged<<<HW_, 256, 0, stream>>>(rots, trans, intrins, post_rots, post_trans,
                                            img_feat, depth_digit, outp);
}